// Round 6
// baseline (168.586 us; speedup 1.0000x reference)
//
#include <hip/hip_runtime.h>
#include <hip/hip_cooperative_groups.h>
#include <math.h>

namespace cg = cooperative_groups;

// (B,T,N,D) = (16,100,128,3), fp32 in, fp32 scalar out.
constexpr int B = 16, T = 100, N = 128;
constexpr float MIN_DIST  = 0.05f;
constexpr float MIN_DIST2 = MIN_DIST * MIN_DIST;

constexpr int THREADS = 256;
constexpr int GRID    = 800;                  // 2 pen slices per block (1600 total)

constexpr int PER_B = T * N * 3;              // 38400 floats per batch
constexpr int PER_T = N * 3;                  // 384 floats per slice

constexpr int WORK_V4_PER_B = (T - 1) * N * 3 / 4;    // 9504
constexpr int WORK_V4 = B * WORK_V4_PER_B;            // 152064
constexpr int KE_V4_PER_SLICE = N * 3 / 4;            // 96
constexpr int KE_V4  = 2 * B * KE_V4_PER_SLICE;       // 3072
constexpr int STAB_V = B * 5 * N;                     // 10240
constexpr int MISC_TOTAL = WORK_V4 + STAB_V + KE_V4;  // 165376 (< GRID*THREADS = 204800)

constexpr int WORK_N = B * (T - 1) * N;               // 202752 (mean divisor)

// ws partial layout: 5 segments of GRID floats each (every slot written every call)
constexpr int SEG_PEN = 0, SEG_WORK = 1, SEG_STAB = 2, SEG_KE0 = 3, SEG_KE1 = 4;

__device__ __forceinline__ float wave_sum(float v) {
#pragma unroll
    for (int off = 32; off > 0; off >>= 1) v += __shfl_down(v, off, 64);
    return v;
}

__global__ __launch_bounds__(THREADS, 4) void physics_one(
    const float* __restrict__ traj, const float* __restrict__ vel,
    const float* __restrict__ frc, float* __restrict__ ws, float* __restrict__ out)
{
    __shared__ float  sraw[2 * PER_T];   // 768 floats: two contiguous slices
    __shared__ float4 spos[2 * N];       // 256 padded points
    __shared__ float  red[5][4];

    const int tid  = threadIdx.x;
    const int bid  = blockIdx.x;
    const int lane = tid & 63;
    const int wv   = tid >> 6;

    // ---- issue pen staging loads (2 slices = 192 float4, fully coalesced) ----
    float4 stg = make_float4(0.f, 0.f, 0.f, 0.f);
    if (tid < 192) stg = ((const float4*)traj)[bid * 192 + tid];

    // ---- misc: exactly one item per thread (overlaps staging latency) ----
    float sw = 0.f, ss = 0.f, kk0 = 0.f, kk1 = 0.f;
    {
        const int v = bid * THREADS + tid;
        if (v < WORK_V4) {
            const int b = v / WORK_V4_PER_B;
            const int r = v - b * WORK_V4_PER_B;
            const int base = b * (PER_B / 4) + r;
            const float4 f  = ((const float4*)frc)[base];
            const float4 t0 = ((const float4*)traj)[base];
            const float4 t1 = ((const float4*)traj)[base + PER_T / 4];
            sw = f.x * (t1.x - t0.x) + f.y * (t1.y - t0.y)
               + f.z * (t1.z - t0.z) + f.w * (t1.w - t0.w);
        } else if (v < WORK_V4 + STAB_V) {
            const int s2 = v - WORK_V4;
            const int b  = s2 / 640;               // 5*N vectors per batch
            const int r  = s2 - b * 640;
            const int e  = b * PER_B + 95 * PER_T + r * 3;
            const float vx = vel[e], vy = vel[e + 1], vz = vel[e + 2];
            ss = sqrtf(vx * vx + vy * vy + vz * vz);
        } else if (v < MISC_TOTAL) {
            const int s2    = v - WORK_V4 - STAB_V;        // [0,3072)
            const int which = s2 / 1536;                   // 0 -> t=0, 1 -> t=T-1
            const int rr    = s2 - which * 1536;
            const int b     = rr / KE_V4_PER_SLICE;
            const int r     = rr - b * KE_V4_PER_SLICE;
            const float4 q  = ((const float4*)vel)[b * (PER_B / 4) + which * (99 * PER_T / 4) + r];
            const float k   = q.x * q.x + q.y * q.y + q.z * q.z + q.w * q.w;
            if (which) kk1 = k; else kk0 = k;
        }
    }

    // ---- finish staging, repack to float4 points ----
    if (tid < 192) ((float4*)sraw)[tid] = stg;
    __syncthreads();
    spos[tid] = make_float4(sraw[3 * tid], sraw[3 * tid + 1], sraw[3 * tid + 2], 0.f);
    __syncthreads();

    // ---- penetration: wrap partition, both slices per iteration ----
    // unordered pair {a,b}: circular dist d=1..63 counted once (k=d from the
    // smaller side), d=64 via diagonal with i<64 guard.
    const int i    = tid & (N - 1);
    const int half = tid >> 7;
    const float4 p0 = spos[i];
    const float4 p1 = spos[N + i];
    float s = 0.f;
    const int klo = 1 + half * 32;                 // half0: 1..32, half1: 33..63
    const int khi = 32 + half * 31;
#pragma unroll 8
    for (int k = klo; k <= khi; ++k) {
        const int j = (i + k) & (N - 1);
        const float4 q0 = spos[j];
        const float4 q1 = spos[N + j];
        float dx = p0.x - q0.x, dy = p0.y - q0.y, dz = p0.z - q0.z;
        const float d2a = dx * dx + dy * dy + dz * dz;
        dx = p1.x - q1.x; dy = p1.y - q1.y; dz = p1.z - q1.z;
        const float d2b = dx * dx + dy * dy + dz * dz;
        const bool ha = d2a < MIN_DIST2;
        const bool hb = d2b < MIN_DIST2;
        if (__builtin_expect(__any(ha | hb), 0)) { // hits ~1e-5/pair: coherent skip
            if (ha) s += MIN_DIST - sqrtf(d2a);
            if (hb) s += MIN_DIST - sqrtf(d2b);
        }
    }
    if (half) {                                    // k = 64 diagonal, count once
        const int j = (i + 64) & (N - 1);
        const float4 q0 = spos[j];
        const float4 q1 = spos[N + j];
        float dx = p0.x - q0.x, dy = p0.y - q0.y, dz = p0.z - q0.z;
        const float d2a = dx * dx + dy * dy + dz * dz;
        dx = p1.x - q1.x; dy = p1.y - q1.y; dz = p1.z - q1.z;
        const float d2b = dx * dx + dy * dy + dz * dz;
        const bool ha = (d2a < MIN_DIST2) & (i < 64);
        const bool hb = (d2b < MIN_DIST2) & (i < 64);
        if (__builtin_expect(__any(ha | hb), 0)) {
            if (ha) s += MIN_DIST - sqrtf(d2a);
            if (hb) s += MIN_DIST - sqrtf(d2b);
        }
    }

    // ---- block reduction of 5 partials ----
    float vals[5] = {s, sw, ss, kk0, kk1};
#pragma unroll
    for (int vv = 0; vv < 5; ++vv) {
        const float w = wave_sum(vals[vv]);
        if (lane == 0) red[vv][wv] = w;
    }
    __syncthreads();
    if (tid == 0) {
#pragma unroll
        for (int vv = 0; vv < 5; ++vv)
            ws[vv * GRID + bid] = red[vv][0] + red[vv][1] + red[vv][2] + red[vv][3];
    }
    __threadfence();

    cg::this_grid().sync();

    // ---- block 0: final reduction + formula ----
    if (bid == 0) {
        float acc[5];
#pragma unroll
        for (int seg = 0; seg < 5; ++seg) {
            float a = 0.f;
            for (int idx = tid; idx < GRID; idx += THREADS) a += ws[seg * GRID + idx];
            acc[seg] = wave_sum(a);
        }
        if (lane == 0) {
#pragma unroll
            for (int seg = 0; seg < 5; ++seg) red[seg][wv] = acc[seg];
        }
        __syncthreads();
        if (tid == 0) {
            const float pen = red[0][0] + red[0][1] + red[0][2] + red[0][3];
            const float wk  = red[1][0] + red[1][1] + red[1][2] + red[1][3];
            const float st  = red[2][0] + red[2][1] + red[2][2] + red[2][3];
            const float k0  = red[3][0] + red[3][1] + red[3][2] + red[3][3];
            const float k1  = red[4][0] + red[4][1] + red[4][2] + red[4][3];
            const float pen_loss  = pen / (float)((long long)B * T * (N * (N - 1) / 2));
            const float stab_loss = st / (float)STAB_V;
            const float ke_s = 0.5f * k0 / (float)(B * N);
            const float ke_e = 0.5f * k1 / (float)(B * N);
            const float work = wk / (float)WORK_N;
            out[0] = 10.0f * pen_loss + stab_loss + 0.1f * fabsf(ke_e - ke_s - work);
        }
    }
}

extern "C" void kernel_launch(void* const* d_in, const int* in_sizes, int n_in,
                              void* d_out, int out_size, void* d_ws, size_t ws_size,
                              hipStream_t stream) {
    const float* traj = (const float*)d_in[0];
    const float* vel  = (const float*)d_in[1];
    const float* frc  = (const float*)d_in[2];
    float* out = (float*)d_out;
    float* ws  = (float*)d_ws;

    void* args[] = {(void*)&traj, (void*)&vel, (void*)&frc, (void*)&ws, (void*)&out};
    hipLaunchCooperativeKernel((const void*)physics_one, dim3(GRID), dim3(THREADS),
                               args, 0, stream);
}

// Round 7
// 68.796 us; speedup vs baseline: 2.4505x; 2.4505x over previous
//
#include <hip/hip_runtime.h>
#include <math.h>

// (B,T,N,D) = (16,100,128,3), fp32 in, fp32 scalar out.
constexpr int B = 16, T = 100, N = 128;
constexpr float MIN_DIST  = 0.05f;
constexpr float MIN_DIST2 = MIN_DIST * MIN_DIST;

constexpr int THREADS     = 256;
constexpr int MISC_BLOCKS = 160;              // scheduled first (streaming)
constexpr int PEN_BLOCKS  = B * T / 2;        // 800 — TWO (b,t) slices per block
constexpr int TOTAL_BLOCKS = MISC_BLOCKS + PEN_BLOCKS;

constexpr int PER_B = T * N * 3;              // 38400 floats per batch
constexpr int PER_T = N * 3;                  // 384 floats per slice

constexpr int WORK_V4_PER_B = (T - 1) * N * 3 / 4;    // 9504
constexpr int WORK_V4 = B * WORK_V4_PER_B;            // 152064
constexpr int KE_V4_PER_SLICE = N * 3 / 4;            // 96
constexpr int KE_V4  = 2 * B * KE_V4_PER_SLICE;       // 3072
constexpr int STAB_V = B * 5 * N;                     // 10240
constexpr int MISC_TOTAL = WORK_V4 + STAB_V + KE_V4;  // 165376

constexpr int WORK_N = B * (T - 1) * N;               // 202752 (mean divisor)

// ws layout (every slot written every call -> no zero-init node):
// [0,800) pen per block | [800,960) work | [960,1120) stab | [1120,1280) ke0 | [1280,1440) ke1
constexpr int WORK_OFF = 800, STAB_OFF = 960, KE0_OFF = 1120, KE1_OFF = 1280;

__device__ __forceinline__ float wave_sum(float v) {
#pragma unroll
    for (int off = 32; off > 0; off >>= 1) v += __shfl_down(v, off, 64);
    return v;
}

__global__ __launch_bounds__(THREADS) void physics_fused(
    const float* __restrict__ traj, const float* __restrict__ vel,
    const float* __restrict__ frc, float* __restrict__ ws)
{
    __shared__ float  sraw[2 * PER_T];   // 768 floats: two contiguous slices
    __shared__ float4 spos[2 * N];       // 256 padded points
    __shared__ float  red[4][4];

    const int tid  = threadIdx.x;
    const int bid  = blockIdx.x;
    const int lane = tid & 63;
    const int wv   = tid >> 6;

    if (bid >= MISC_BLOCKS) {
        // ---- penetration: two (b,t) slices, unordered pairs once each ----
        const int pb = bid - MISC_BLOCKS;
        if (tid < 192)
            ((float4*)sraw)[tid] = ((const float4*)traj)[pb * 192 + tid];
        __syncthreads();
        spos[tid] = make_float4(sraw[3 * tid], sraw[3 * tid + 1], sraw[3 * tid + 2], 0.f);
        __syncthreads();

        // thread = (slice, point): tid 0..127 -> slice0, 128..255 -> slice1
        const int i  = tid & (N - 1);
        const int sb = (tid >> 7) * N;             // slice base in spos
        const float4 pi = spos[sb + i];
        float s = 0.f;
        // wrap partition: k=1..63 counts each circular-distance-d pair once
#pragma unroll 9
        for (int k = 1; k <= 63; ++k) {
            const int j = sb + ((i + k) & (N - 1));  // stride-1 across lanes
            const float4 pj = spos[j];
            const float dx = pi.x - pj.x, dy = pi.y - pj.y, dz = pi.z - pj.z;
            const float d2 = dx * dx + dy * dy + dz * dz;
            const bool h = d2 < MIN_DIST2;
            if (__builtin_expect(__any(h), 0))     // hits ~1e-5/pair: coherent skip
                if (h) s += MIN_DIST - sqrtf(d2);
        }
        {                                          // d = 64 diagonal, count once
            const float4 pj = spos[sb + ((i + 64) & (N - 1))];
            const float dx = pi.x - pj.x, dy = pi.y - pj.y, dz = pi.z - pj.z;
            const float d2 = dx * dx + dy * dy + dz * dz;
            const bool h = (d2 < MIN_DIST2) & (i < 64);
            if (__builtin_expect(__any(h), 0))
                if (h) s += MIN_DIST - sqrtf(d2);
        }
        float w = wave_sum(s);
        if (lane == 0) red[0][wv] = w;
        __syncthreads();
        if (tid == 0)
            ws[pb] = red[0][0] + red[0][1] + red[0][2] + red[0][3];
    } else {
        // ---- work / stability / kinetic: vectorized grid-stride ----
        const int mb = bid;
        const float4* t4 = (const float4*)traj;
        const float4* f4 = (const float4*)frc;
        const float4* v4 = (const float4*)vel;
        float sw = 0.f, ss = 0.f, k0 = 0.f, k1 = 0.f;
        const int stride = MISC_BLOCKS * THREADS;
        for (int v = mb * THREADS + tid; v < MISC_TOTAL; v += stride) {
            if (v < WORK_V4) {
                const int b = v / WORK_V4_PER_B;
                const int r = v - b * WORK_V4_PER_B;
                const int base = b * (PER_B / 4) + r;
                const float4 f  = f4[base];
                const float4 t0 = t4[base];
                const float4 t1 = t4[base + PER_T / 4];
                sw += f.x * (t1.x - t0.x) + f.y * (t1.y - t0.y)
                    + f.z * (t1.z - t0.z) + f.w * (t1.w - t0.w);
            } else if (v < WORK_V4 + STAB_V) {
                const int s2 = v - WORK_V4;
                const int b  = s2 / 640;           // 5*N vectors per batch
                const int r  = s2 - b * 640;
                const int e  = b * PER_B + 95 * PER_T + r * 3;
                const float vx = vel[e], vy = vel[e + 1], vz = vel[e + 2];
                ss += sqrtf(vx * vx + vy * vy + vz * vz);
            } else {
                const int s2    = v - WORK_V4 - STAB_V;      // [0,3072)
                const int which = s2 / 1536;                 // 0 -> t=0, 1 -> t=T-1
                const int rr    = s2 - which * 1536;
                const int b     = rr / KE_V4_PER_SLICE;
                const int r     = rr - b * KE_V4_PER_SLICE;
                const float4 q  = v4[b * (PER_B / 4) + which * (99 * PER_T / 4) + r];
                const float k   = q.x * q.x + q.y * q.y + q.z * q.z + q.w * q.w;
                if (which) k1 += k; else k0 += k;
            }
        }
        float vals[4] = {sw, ss, k0, k1};
#pragma unroll
        for (int vv = 0; vv < 4; ++vv) {
            const float w = wave_sum(vals[vv]);
            if (lane == 0) red[vv][wv] = w;
        }
        __syncthreads();
        if (tid == 0) {
            ws[WORK_OFF + mb] = red[0][0] + red[0][1] + red[0][2] + red[0][3];
            ws[STAB_OFF + mb] = red[1][0] + red[1][1] + red[1][2] + red[1][3];
            ws[KE0_OFF  + mb] = red[2][0] + red[2][1] + red[2][2] + red[2][3];
            ws[KE1_OFF  + mb] = red[3][0] + red[3][1] + red[3][2] + red[3][3];
        }
    }
}

__global__ __launch_bounds__(256) void physics_finalize(
    const float* __restrict__ ws, float* __restrict__ out)
{
    __shared__ float redP[4], redM[4];
    const int tid = threadIdx.x, lane = tid & 63, wv = tid >> 6;

    float p = 0.f;
    for (int i = tid; i < PEN_BLOCKS; i += 256) p += ws[i];

    const int base = WORK_OFF + 160 * wv;   // wave wv: work/stab/ke0/ke1 segment
    float m = ws[base + lane] + ws[base + 64 + lane]
            + (lane < 32 ? ws[base + 128 + lane] : 0.f);

    p = wave_sum(p);
    m = wave_sum(m);
    if (lane == 0) { redP[wv] = p; redM[wv] = m; }
    __syncthreads();

    if (tid == 0) {
        const float pen = redP[0] + redP[1] + redP[2] + redP[3];
        const float wk = redM[0], st = redM[1], k0 = redM[2], k1 = redM[3];
        const float pen_loss  = pen / (float)((long long)B * T * (N * (N - 1) / 2));
        const float stab_loss = st / (float)STAB_V;
        const float ke_s = 0.5f * k0 / (float)(B * N);
        const float ke_e = 0.5f * k1 / (float)(B * N);
        const float work = wk / (float)WORK_N;
        out[0] = 10.0f * pen_loss + stab_loss + 0.1f * fabsf(ke_e - ke_s - work);
    }
}

extern "C" void kernel_launch(void* const* d_in, const int* in_sizes, int n_in,
                              void* d_out, int out_size, void* d_ws, size_t ws_size,
                              hipStream_t stream) {
    const float* traj = (const float*)d_in[0];
    const float* vel  = (const float*)d_in[1];
    const float* frc  = (const float*)d_in[2];
    float* out = (float*)d_out;
    float* ws  = (float*)d_ws;

    physics_fused<<<TOTAL_BLOCKS, THREADS, 0, stream>>>(traj, vel, frc, ws);
    physics_finalize<<<1, 256, 0, stream>>>(ws, out);
}